// Round 8
// baseline (665.348 us; speedup 1.0000x reference)
//
#include <hip/hip_runtime.h>

// ---------- bf16 helpers (manual, RNE) ----------
__device__ __forceinline__ unsigned short f2bf(float f) {
  union { float f; unsigned int i; } c; c.f = f;
  unsigned int i = c.i;
  i += 0x7fffu + ((i >> 16) & 1u);
  return (unsigned short)(i >> 16);
}

typedef __attribute__((ext_vector_type(8))) short bf16x8;
typedef __attribute__((ext_vector_type(4))) float f32x4;

// Geometry: x is (bt=8, C=128, 64, 64); bt = b*4 + t (b=2, t=4).
// Head group g (0..3): patch p = 1<<(g+1), dk = 32 channels.
// Packed token layout per group: (b, l, d); L*D = 1<<19; group base = g<<20.
// MFMA convention (verified):
//   A-frag: lane(ml=lane&15,kg=lane>>4) holds A[row=ml][c=kg*8+j]
//   B-frag: lane holds B[c=kg*8+j][col=ml]
//   C/D   : lane holds D[row=kg*4+reg][col=ml]
// g0 fragment-major layouts (contiguous 1KB per wave frag-load):
//   Qf[b][qt][cc4][lane64][8]   element (q=qt*16+ml, d=cc*32+kg*8+j)
//   Kf[b][ck64][cc4][mf4][lane64][8]  (key=ck*64+mf*16+ml, d=cc*32+kg*8+j)
//   Vf[b][ck64][nf8][part2][lane64][8] (key=ck*64+part*32+kg*8+j, d=nf*16+ml)

// ---------- x (NCHW f32) -> x_hwc (pix_g, 128) bf16 ----------
__global__ __launch_bounds__(256) void x2hwc(const float* __restrict__ X,
                                             unsigned short* __restrict__ Xh) {
  int pixg = blockIdx.x * 256 + threadIdx.x;  // 32768
  int c0 = blockIdx.y * 8;
  int bt = pixg >> 12, pix = pixg & 4095;
  const float* src = X + ((size_t)bt << 19) + (size_t)c0 * 4096 + pix;
  unsigned int pk[4];
#pragma unroll
  for (int j = 0; j < 4; j++) {
    unsigned short u0 = f2bf(src[(2 * j) * 4096]);
    unsigned short u1 = f2bf(src[(2 * j + 1) * 4096]);
    pk[j] = (unsigned int)u0 | ((unsigned int)u1 << 16);
  }
  *(uint4*)(Xh + (size_t)pixg * 128 + c0) = make_uint4(pk[0], pk[1], pk[2], pk[3]);
}

// ---------- weight prep 3x3: (o,i,3,3) f32 -> fragment-major bf16 ----------
__global__ __launch_bounds__(256) void wprep3(
    const float* __restrict__ s0, const float* __restrict__ s1,
    const float* __restrict__ s2, unsigned short* __restrict__ d0,
    unsigned short* __restrict__ d1, unsigned short* __restrict__ d2) {
  int idx = blockIdx.x * 256 + threadIdx.x;  // 147456
  const float* s = blockIdx.y == 0 ? s0 : (blockIdx.y == 1 ? s1 : s2);
  unsigned short* d = blockIdx.y == 0 ? d0 : (blockIdx.y == 1 ? d1 : d2);
  int j = idx & 7;
  int lane = (idx >> 3) & 63;
  int kg = lane >> 4, ml = lane & 15;
  int f = idx >> 9;
  int mf = f & 3, wm = (f >> 2) & 1, cs = (f >> 3) & 3, tap = f >> 5;
  int o = wm * 64 + mf * 16 + ml;
  int i = cs * 32 + kg * 8 + j;
  d[idx] = f2bf(s[(size_t)(o * 128 + i) * 9 + tap]);
}

// ---------- weight prep 1x1 ----------
__global__ __launch_bounds__(256) void wprep1(
    const float* __restrict__ s0, const float* __restrict__ s1,
    const float* __restrict__ s2, unsigned short* __restrict__ d0,
    unsigned short* __restrict__ d1, unsigned short* __restrict__ d2) {
  int idx = blockIdx.x * 256 + threadIdx.x;  // 16384
  const float* s = blockIdx.y == 0 ? s0 : (blockIdx.y == 1 ? s1 : s2);
  unsigned short* d = blockIdx.y == 0 ? d0 : (blockIdx.y == 1 ? d1 : d2);
  d[idx] = f2bf(s[idx]);
}

// ---------- QKV projection MFMA GEMM with pack epilogue ----------
template <int MODE>
__global__ __launch_bounds__(256) void qkv_pack(
    const unsigned short* __restrict__ Xh, const unsigned short* __restrict__ Wb,
    const float* __restrict__ Bi, unsigned short* __restrict__ P,
    unsigned short* __restrict__ VtP, unsigned short* __restrict__ Ff) {
  int tid = threadIdx.x, lane = tid & 63, wid = tid >> 6;
  int wm = wid & 1, wn = wid >> 1;
  int ml = lane & 15, kg = lane >> 4;
  int m_base = blockIdx.y * 64 + wm * 32;
  int n_base = blockIdx.x * 64 + wn * 32;
  f32x4 acc[2][2];
#pragma unroll
  for (int i = 0; i < 2; i++)
#pragma unroll
    for (int j = 0; j < 2; j++) acc[i][j] = {0.f, 0.f, 0.f, 0.f};
#pragma unroll
  for (int kc = 0; kc < 128; kc += 32) {
    bf16x8 af[2], bfr[2];
#pragma unroll
    for (int mf = 0; mf < 2; mf++)
      af[mf] = *(const bf16x8*)(Wb + (size_t)(m_base + mf * 16 + ml) * 128 + kc + kg * 8);
#pragma unroll
    for (int nf = 0; nf < 2; nf++)
      bfr[nf] = *(const bf16x8*)(Xh + (size_t)(n_base + nf * 16 + ml) * 128 + kc + kg * 8);
#pragma unroll
    for (int mf = 0; mf < 2; mf++)
#pragma unroll
      for (int nf = 0; nf < 2; nf++)
        acc[mf][nf] = __builtin_amdgcn_mfma_f32_16x16x32_bf16(af[mf], bfr[nf], acc[mf][nf], 0, 0, 0);
  }
#pragma unroll
  for (int mf = 0; mf < 2; mf++)
#pragma unroll
    for (int nf = 0; nf < 2; nf++)
#pragma unroll
      for (int r = 0; r < 4; r++) {
        int c = m_base + mf * 16 + kg * 4 + r;
        int pixg = n_base + nf * 16 + ml;
        float val = acc[mf][nf][r] + Bi[c];
        int bt = pixg >> 12, pix = pixg & 4095;
        int h = pix >> 6, w = pix & 63;
        int g = c >> 5, sh = g + 1, msk = (1 << sh) - 1, ohn = 64 >> sh;
        int b = bt >> 2, t_i = bt & 3;
        int l = (t_i * ohn + (h >> sh)) * ohn + (w >> sh);
        int Dg = 32 << (2 * sh);
        int d = ((c & 31) << (2 * sh)) + ((h & msk) << sh) + (w & msk);
        if (MODE == 0) val *= rsqrtf((float)Dg);
        unsigned short bv = f2bf(val);
        size_t bofs = (size_t)b << 19;
        if (g == 0) {
          if (MODE == 0) {
            int qt = l >> 4, mlq = l & 15, cc = d >> 5, kgq = (d >> 3) & 3, j = d & 7;
            Ff[bofs + ((size_t)(qt * 4 + cc) << 9) + (kgq * 16 + mlq) * 8 + j] = bv;
          } else if (MODE == 1) {
            int ck = l >> 6, mfk = (l >> 4) & 3, mlk = l & 15;
            int cc = d >> 5, kgk = (d >> 3) & 3, j = d & 7;
            Ff[bofs + ((size_t)(ck * 16 + cc * 4 + mfk) << 9) + (kgk * 16 + mlk) * 8 + j] = bv;
          } else {
            int ck = l >> 6, part = (l >> 5) & 1, kgv = (l >> 3) & 3, j = l & 7;
            int nf = d >> 4, mlv = d & 15;
            Ff[bofs + ((size_t)(ck * 16 + nf * 2 + part) << 9) + (kgv * 16 + mlv) * 8 + j] = bv;
          }
        } else {
          size_t base = ((size_t)g << 20) + bofs;
          if (MODE != 2) {
            P[base + (size_t)l * Dg + d] = bv;
          } else {
            int Lg = 16384 >> (2 * sh);
            VtP[base + (size_t)d * Lg + l] = bv;
          }
        }
      }
}

// ---------- generic MFMA GEMM: C(MxN) f32 = A(MxK) * B(NxK)^T, bf16 ----------
__global__ __launch_bounds__(256) void gemm_tn(
    const unsigned short* __restrict__ A, const unsigned short* __restrict__ B,
    float* __restrict__ C, int K, int lda, int ldb, int ldc,
    long long sA, long long sB, long long sC) {
  int tid = threadIdx.x, lane = tid & 63, wid = tid >> 6;
  int wm = wid & 1, wn = wid >> 1;
  int ml = lane & 15, kg = lane >> 4;
  A += (size_t)blockIdx.z * sA;
  B += (size_t)blockIdx.z * sB;
  C += (size_t)blockIdx.z * sC;
  int m_base = blockIdx.y * 64 + wm * 32;
  int n_base = blockIdx.x * 64 + wn * 32;
  f32x4 acc[2][2];
#pragma unroll
  for (int i = 0; i < 2; i++)
#pragma unroll
    for (int j = 0; j < 2; j++) acc[i][j] = {0.f, 0.f, 0.f, 0.f};
  for (int kc = 0; kc < K; kc += 32) {
    bf16x8 af[2], bfr[2];
#pragma unroll
    for (int mf = 0; mf < 2; mf++)
      af[mf] = *(const bf16x8*)(A + (size_t)(m_base + mf * 16 + ml) * lda + kc + kg * 8);
#pragma unroll
    for (int nf = 0; nf < 2; nf++)
      bfr[nf] = *(const bf16x8*)(B + (size_t)(n_base + nf * 16 + ml) * ldb + kc + kg * 8);
#pragma unroll
    for (int mf = 0; mf < 2; mf++)
#pragma unroll
      for (int nf = 0; nf < 2; nf++)
        acc[mf][nf] = __builtin_amdgcn_mfma_f32_16x16x32_bf16(af[mf], bfr[nf], acc[mf][nf], 0, 0, 0);
  }
#pragma unroll
  for (int mf = 0; mf < 2; mf++)
#pragma unroll
    for (int nf = 0; nf < 2; nf++)
#pragma unroll
      for (int r = 0; r < 4; r++) {
        int m = m_base + mf * 16 + kg * 4 + r;
        int n = n_base + nf * 16 + ml;
        C[(size_t)m * ldc + n] = acc[mf][nf][r];
      }
}

// ---------- split-K MFMA GEMM (square, KC=128): partial tiles ----------
__global__ __launch_bounds__(256) void gemm_tn_sk(
    const unsigned short* __restrict__ A, const unsigned short* __restrict__ B,
    float* __restrict__ Cp, int lda, int ldb, int L,
    long long sA, long long sB) {
  constexpr int KC = 128;
  int tid = threadIdx.x, lane = tid & 63, wid = tid >> 6;
  int wm = wid & 1, wn = wid >> 1;
  int ml = lane & 15, kg = lane >> 4;
  int bz = blockIdx.z, b = bz & 1, split = bz >> 1;
  A += (size_t)b * sA + split * KC;
  B += (size_t)b * sB + split * KC;
  float* Ct = Cp + (size_t)bz * L * L;
  int m_base = blockIdx.y * 64 + wm * 32;
  int n_base = blockIdx.x * 64 + wn * 32;
  f32x4 acc[2][2];
#pragma unroll
  for (int i = 0; i < 2; i++)
#pragma unroll
    for (int j = 0; j < 2; j++) acc[i][j] = {0.f, 0.f, 0.f, 0.f};
#pragma unroll
  for (int kc = 0; kc < KC; kc += 32) {
    bf16x8 af[2], bfr[2];
#pragma unroll
    for (int mf = 0; mf < 2; mf++)
      af[mf] = *(const bf16x8*)(A + (size_t)(m_base + mf * 16 + ml) * lda + kc + kg * 8);
#pragma unroll
    for (int nf = 0; nf < 2; nf++)
      bfr[nf] = *(const bf16x8*)(B + (size_t)(n_base + nf * 16 + ml) * ldb + kc + kg * 8);
#pragma unroll
    for (int mf = 0; mf < 2; mf++)
#pragma unroll
      for (int nf = 0; nf < 2; nf++)
        acc[mf][nf] = __builtin_amdgcn_mfma_f32_16x16x32_bf16(af[mf], bfr[nf], acc[mf][nf], 0, 0, 0);
  }
#pragma unroll
  for (int mf = 0; mf < 2; mf++)
#pragma unroll
    for (int nf = 0; nf < 2; nf++)
#pragma unroll
      for (int r = 0; r < 4; r++) {
        int m = m_base + mf * 16 + kg * 4 + r;
        int n = n_base + nf * 16 + ml;
        Ct[(size_t)m * L + n] = acc[mf][nf][r];
      }
}

// ---------- split-K MFMA GEMM, 2 splits, general ldc (for PV) ----------
// grid (N/64, M/64, 4): bz: b=bz&1, split=bz>>1; Cp[bz][M][N].
__global__ __launch_bounds__(256) void gemm_tn_sk2(
    const unsigned short* __restrict__ A, const unsigned short* __restrict__ B,
    float* __restrict__ Cp, int KC, int lda, int ldb, int ldc,
    long long sA, long long sB) {
  int tid = threadIdx.x, lane = tid & 63, wid = tid >> 6;
  int wm = wid & 1, wn = wid >> 1;
  int ml = lane & 15, kg = lane >> 4;
  int bz = blockIdx.z, b = bz & 1, split = bz >> 1;
  A += (size_t)b * sA + (size_t)split * KC;
  B += (size_t)b * sB + (size_t)split * KC;
  size_t MN = (size_t)gridDim.y * 64 * ldc;
  float* Ct = Cp + (size_t)bz * MN;
  int m_base = blockIdx.y * 64 + wm * 32;
  int n_base = blockIdx.x * 64 + wn * 32;
  f32x4 acc[2][2];
#pragma unroll
  for (int i = 0; i < 2; i++)
#pragma unroll
    for (int j = 0; j < 2; j++) acc[i][j] = {0.f, 0.f, 0.f, 0.f};
  for (int kc = 0; kc < KC; kc += 32) {
    bf16x8 af[2], bfr[2];
#pragma unroll
    for (int mf = 0; mf < 2; mf++)
      af[mf] = *(const bf16x8*)(A + (size_t)(m_base + mf * 16 + ml) * lda + kc + kg * 8);
#pragma unroll
    for (int nf = 0; nf < 2; nf++)
      bfr[nf] = *(const bf16x8*)(B + (size_t)(n_base + nf * 16 + ml) * ldb + kc + kg * 8);
#pragma unroll
    for (int mf = 0; mf < 2; mf++)
#pragma unroll
      for (int nf = 0; nf < 2; nf++)
        acc[mf][nf] = __builtin_amdgcn_mfma_f32_16x16x32_bf16(af[mf], bfr[nf], acc[mf][nf], 0, 0, 0);
  }
#pragma unroll
  for (int mf = 0; mf < 2; mf++)
#pragma unroll
    for (int nf = 0; nf < 2; nf++)
#pragma unroll
      for (int r = 0; r < 4; r++) {
        int m = m_base + mf * 16 + kg * 4 + r;
        int n = n_base + nf * 16 + ml;
        Ct[(size_t)m * ldc + n] = acc[mf][nf][r];
      }
}

// ---------- sum 2 split-K partials -> Out (f32, batch stride sOut) ----------
__global__ __launch_bounds__(256) void sum2(const float* __restrict__ Cp,
                                            float* __restrict__ Out,
                                            int MNq, long long sOut) {
  int idx = blockIdx.x * 256 + threadIdx.x;  // 2*MNq
  int b = idx / MNq, r = idx - b * MNq;
  const float4* c4 = (const float4*)Cp;
  float4 v0 = c4[(size_t)b * MNq + r];
  float4 v1 = c4[(size_t)(2 + b) * MNq + r];
  float4 o = make_float4(v0.x + v1.x, v0.y + v1.y, v0.z + v1.z, v0.w + v1.w);
  ((float4*)(Out + (size_t)b * sOut))[r] = o;
}

// ---------- sum partials + row softmax -> bf16 (L <= 256) ----------
__global__ __launch_bounds__(256) void softmax_sum_bf16(
    const float* __restrict__ Sp, unsigned short* __restrict__ P, int L, int nsplit) {
  __shared__ float red[256];
  int tid = threadIdx.x;
  int b = blockIdx.x / L, m = blockIdx.x - b * L;
  const float* row = Sp + ((size_t)b * L + m) * L;
  long long pstride = 2LL * L * L;
  float val = 0.f;
  if (tid < L) {
    for (int s = 0; s < nsplit; s++) val += row[(size_t)s * pstride + tid];
  }
  red[tid] = (tid < L) ? val : -1e30f;
  __syncthreads();
  for (int s = 128; s > 0; s >>= 1) {
    if (tid < s) red[tid] = fmaxf(red[tid], red[tid + s]);
    __syncthreads();
  }
  float mx = red[0]; __syncthreads();
  float e = (tid < L) ? __expf(val - mx) : 0.f;
  red[tid] = e; __syncthreads();
  for (int s = 128; s > 0; s >>= 1) {
    if (tid < s) red[tid] += red[tid + s];
    __syncthreads();
  }
  float inv = 1.f / red[0];
  if (tid < L) P[((size_t)b * L + m) * L + tid] = f2bf(e * inv);
}

// ---------- row softmax f32 -> bf16 (large L) ----------
__global__ __launch_bounds__(256) void softmax_bf16(float* __restrict__ S,
                                                    unsigned short* __restrict__ P, int L) {
  __shared__ float red[256];
  int tid = threadIdx.x;
  float* p = S + (size_t)blockIdx.x * L;
  unsigned short* o = P + (size_t)blockIdx.x * L;
  float mx = -1e30f;
  for (int e = tid; e < L; e += 256) mx = fmaxf(mx, p[e]);
  red[tid] = mx; __syncthreads();
  for (int s = 128; s > 0; s >>= 1) {
    if (tid < s) red[tid] = fmaxf(red[tid], red[tid + s]);
    __syncthreads();
  }
  mx = red[0]; __syncthreads();
  float sm = 0.f;
  for (int e = tid; e < L; e += 256) {
    float v = __expf(p[e] - mx);
    p[e] = v; sm += v;
  }
  red[tid] = sm; __syncthreads();
  for (int s = 128; s > 0; s >>= 1) {
    if (tid < s) red[tid] += red[tid + s];
    __syncthreads();
  }
  float inv = 1.f / red[0];
  for (int e = tid; e < L; e += 256) o[e] = f2bf(p[e] * inv);
}

// ---------- MFMA flash attention group 0, block-level K-split ----------
// grid (512, 2): bx -> (b, qt); by = K-half (2048 keys). 4 waves x 8 chunks.
// Outputs UNNORMALIZED O~ per half + (M, L) per q; flash_merge combines.
__global__ __launch_bounds__(256, 3) void flash_mfma(
    const unsigned short* __restrict__ Qf, const unsigned short* __restrict__ Kf,
    const unsigned short* __restrict__ Vf, float* __restrict__ Opart,
    float* __restrict__ MLp) {
  __shared__ float Ot[4][16][128];
  __shared__ unsigned short Pl[4][16][72];
  __shared__ float Ml[4][16], Ll[4][16];
  int tid = threadIdx.x, lane = tid & 63, wv = tid >> 6;
  int ml = lane & 15, kg = lane >> 4;
  int b = blockIdx.x >> 8, qt = blockIdx.x & 255;
  int half = blockIdx.y;
  size_t bofs = (size_t)b << 19;
  int q0 = qt * 16;

  bf16x8 qf[4];
#pragma unroll
  for (int cc = 0; cc < 4; cc++)
    qf[cc] = *(const bf16x8*)(Qf + bofs + ((size_t)(qt * 4 + cc) << 9) + lane * 8);

  float m_i = -1e30f, l_i = 0.f;
  f32x4 of[8];
#pragma unroll
  for (int nf = 0; nf < 8; nf++) of[nf] = {0.f, 0.f, 0.f, 0.f};

  int ck0 = half * 32 + wv * 8;
  for (int ck = ck0; ck < ck0 + 8; ck++) {
    const unsigned short* Kc = Kf + bofs + ((size_t)ck << 13);
    const unsigned short* Vc = Vf + bofs + ((size_t)ck << 13);
    // S^T = K x Q
    f32x4 st[4];
#pragma unroll
    for (int mf = 0; mf < 4; mf++) st[mf] = {0.f, 0.f, 0.f, 0.f};
    __builtin_amdgcn_s_setprio(1);
#pragma unroll
    for (int cc = 0; cc < 4; cc++)
#pragma unroll
      for (int mf = 0; mf < 4; mf++) {
        bf16x8 kf = *(const bf16x8*)(Kc + ((cc * 4 + mf) << 9) + lane * 8);
        st[mf] = __builtin_amdgcn_mfma_f32_16x16x32_bf16(kf, qf[cc], st[mf], 0, 0, 0);
      }
    __builtin_amdgcn_s_setprio(0);
    // hoist V loads: latency hides under the softmax chain
    bf16x8 vf[16];
#pragma unroll
    for (int nv = 0; nv < 16; nv++)
      vf[nv] = *(const bf16x8*)(Vc + (nv << 9) + lane * 8);
    // online softmax for q = ml
    float cmax = -1e30f;
#pragma unroll
    for (int mf = 0; mf < 4; mf++)
#pragma unroll
      for (int r = 0; r < 4; r++) cmax = fmaxf(cmax, st[mf][r]);
    cmax = fmaxf(cmax, __shfl_xor(cmax, 16));
    cmax = fmaxf(cmax, __shfl_xor(cmax, 32));
    int skip = __all(cmax <= m_i);  // wave-uniform; alpha==1 path is exact
    float mnew = skip ? m_i : fmaxf(m_i, cmax);
    float p[4][4];
    float psum = 0.f;
#pragma unroll
    for (int mf = 0; mf < 4; mf++)
#pragma unroll
      for (int r = 0; r < 4; r++) {
        float pv = __expf(st[mf][r] - mnew);
        p[mf][r] = pv; psum += pv;
      }
    psum += __shfl_xor(psum, 16);
    psum += __shfl_xor(psum, 32);
    if (skip) {
      l_i += psum;
    } else {
      float alpha = __expf(m_i - mnew);
      l_i = l_i * alpha + psum;
      m_i = mnew;
      float a0 = __shfl(alpha, kg * 4 + 0), a1 = __shfl(alpha, kg * 4 + 1);
      float a2 = __shfl(alpha, kg * 4 + 2), a3 = __shfl(alpha, kg * 4 + 3);
#pragma unroll
      for (int nf = 0; nf < 8; nf++) {
        of[nf][0] *= a0; of[nf][1] *= a1; of[nf][2] *= a2; of[nf][3] *= a3;
      }
    }
#pragma unroll
    for (int mf = 0; mf < 4; mf++) {
      unsigned int lo = (unsigned int)f2bf(p[mf][0]) | ((unsigned int)f2bf(p[mf][1]) << 16);
      unsigned int hi = (unsigned int)f2bf(p[mf][2]) | ((unsigned int)f2bf(p[mf][3]) << 16);
      *(uint2*)&Pl[wv][ml][mf * 16 + kg * 4] = make_uint2(lo, hi);
    }
    bf16x8 pa0 = *(const bf16x8*)&Pl[wv][ml][kg * 8];
    bf16x8 pa1 = *(const bf16x8*)&Pl[wv][ml][32 + kg * 8];
    __builtin_amdgcn_s_setprio(1);
#pragma unroll
    for (int nf = 0; nf < 8; nf++) {
      of[nf] = __builtin_amdgcn_mfma_f32_16x16x32_bf16(pa0, vf[nf * 2 + 0], of[nf], 0, 0, 0);
      of[nf] = __builtin_amdgcn_mfma_f32_16x16x32_bf16(pa1, vf[nf * 2 + 1], of[nf], 0, 0, 0);
    }
    __builtin_amdgcn_s_setprio(0);
  }

  // merge 4 waves (unnormalized): O~ = sum_w e^{m_w - mt} of_w; lt = sum e^{m_w-mt} l_w
  if (kg == 0) { Ml[wv][ml] = m_i; Ll[wv][ml] = l_i; }
  __syncthreads();
  float m0 = Ml[0][ml], m1 = Ml[1][ml], m2 = Ml[2][ml], m3 = Ml[3][ml];
  float mt = fmaxf(fmaxf(m0, m1), fmaxf(m2, m3));
  float lt = Ll[0][ml] * __expf(m0 - mt) + Ll[1][ml] * __expf(m1 - mt) +
             Ll[2][ml] * __expf(m2 - mt) + Ll[3][ml] * __expf(m3 - mt);
  float s = __expf(m_i - mt);
  float s0 = __shfl(s, kg * 4 + 0), s1 = __shfl(s, kg * 4 + 1);
  float s2 = __shfl(s, kg * 4 + 2), s3 = __shfl(s, kg * 4 + 3);
#pragma unroll
  for (int nf = 0; nf < 8; nf++) {
    Ot[wv][kg * 4 + 0][nf * 16 + ml] = of[nf][0] * s0;
    Ot[wv][kg * 4 + 1][nf * 16 + ml] = of[nf][1] * s1;
    Ot[wv][kg * 4 + 2][nf * 16 + ml] = of[nf][2] * s2;
    Ot[wv][kg * 4 + 3][nf * 16 + ml] = of[nf][3] * s3;
  }
  if (wv == 0 && kg == 0) {
    MLp[half * 16384 + b * 8192 + q0 + ml] = mt;
    MLp[half * 16384 + b * 8192 + 4096 + q0 + ml] = lt;
  }
  __syncthreads();
  int base = tid * 8;
  int q = base >> 7, d = base & 127;
  float4 r0 = make_float4(0, 0, 0, 0), r1 = make_float4(0, 0, 0, 0);
#pragma unroll
  for (int w = 0; w < 4; w++) {
    float4 a = *(const float4*)&Ot[w][q][d];
    float4 c = *(const float4*)&Ot[w][q][d + 4];
    r0.x += a.x; r0.y += a.y; r0.z += a.z; r0.w += a.w;
    r1.x += c.x; r1.y += c.y; r1.z += c.z; r1.w += c.w;
  }
  float* Op = Opart + ((size_t)half << 20) + bofs + (size_t)(q0 + q) * 128 + d;
  *(float4*)Op = r0;
  *(float4*)(Op + 4) = r1;
}

// ---------- merge the two flash K-halves ----------
__global__ __launch_bounds__(256) void flash_merge(
    const float* __restrict__ Op, const float* __restrict__ MLp,
    float* __restrict__ O) {
  int idx = blockIdx.x * 256 + threadIdx.x;  // 262144: (b, q, d4)
  int b = idx >> 17, rem = idx & 131071;
  int q = rem >> 5, d4 = (rem & 31) << 2;
  float M0 = MLp[b * 8192 + q], L0 = MLp[b * 8192 + 4096 + q];
  float M1 = MLp[16384 + b * 8192 + q], L1 = MLp[16384 + b * 8192 + 4096 + q];
  float M = fmaxf(M0, M1);
  float e0 = __expf(M0 - M), e1 = __expf(M1 - M);
  float inv = 1.f / (e0 * L0 + e1 * L1);
  size_t o0 = ((size_t)b << 19) + (size_t)q * 128 + d4;
  float4 a = *(const float4*)(Op + o0);
  float4 c = *(const float4*)(Op + (1 << 20) + o0);
  float4 r = make_float4((e0 * a.x + e1 * c.x) * inv, (e0 * a.y + e1 * c.y) * inv,
                         (e0 * a.z + e1 * c.z) * inv, (e0 * a.w + e1 * c.w) * inv);
  *(float4*)(O + o0) = r;
}

// ---------- unpack packed attention output to bf16 (bt,h,w,C) ----------
__global__ __launch_bounds__(256) void unpack_att_bf16(
    const float* __restrict__ opk, unsigned short* __restrict__ att) {
  int idx = blockIdx.x * 256 + threadIdx.x;
  int oct = idx & 15, pix = idx >> 4;
  int w = pix & 63, h = (pix >> 6) & 63, bt = pix >> 12;
  int c0 = oct * 8;
  int g = c0 >> 5;
  int sh = g + 1, msk = (1 << sh) - 1;
  int ohn = 64 >> sh;
  int b = bt >> 2, t_i = bt & 3;
  int l = (t_i * ohn + (h >> sh)) * ohn + (w >> sh);
  int Dg = 32 << (2 * sh);
  int dbase = ((c0 & 31) << (2 * sh)) + ((h & msk) << sh) + (w & msk);
  const float* src = opk + ((size_t)g << 20) + ((size_t)b << 19) + (size_t)l * Dg;
  int dstep = 1 << (2 * sh);
  unsigned int pk[4];
#pragma unroll
  for (int j = 0; j < 4; j++) {
    unsigned short u0 = f2bf(src[dbase + (2 * j) * dstep]);
    unsigned short u1 = f2bf(src[dbase + (2 * j + 1) * dstep]);
    pk[j] = (unsigned int)u0 | ((unsigned int)u1 << 16);
  }
  *(uint4*)(att + ((size_t)pix * 128 + c0)) = make_uint4(pk[0], pk[1], pk[2], pk[3]);
}

// ---------- MFMA implicit-GEMM 3x3 conv: LDS row-staged, frag-major weights ----------
template <int DIL, bool WF32, bool WBF16, bool RES>
__global__ __launch_bounds__(256) void conv_mfma(
    const unsigned short* __restrict__ Xb,
    const unsigned short* __restrict__ Wt,
    const float* __restrict__ Bi,
    const float* __restrict__ Rs,
    float* __restrict__ Yf,
    unsigned short* __restrict__ Ybf) {
  __shared__ __align__(16) char Xs[3 * 17408];
  int tid = threadIdx.x;
  int lane = tid & 63, wid = tid >> 6;
  int wm = wid & 1, wn = wid >> 1;
  int ml = lane & 15, kg = lane >> 4;
  int bt = blockIdx.x >> 6, h = blockIdx.x & 63;
  const int wbase = wn * 32;

  for (int idx = tid; idx < 3264; idx += 256) {
    int row = idx / 1088, rem = idx - row * 1088;
    int pix = rem >> 4, cs = rem & 15;
    int r = h + (row - 1) * DIL;
    int w = pix - 2;
    bf16x8 v = {0, 0, 0, 0, 0, 0, 0, 0};
    if ((unsigned)r < 64u && (unsigned)w < 64u)
      v = *(const bf16x8*)(Xb + (((size_t)(bt * 64 + r) * 64 + w) << 7) + cs * 8);
    int sw = (cs & 8) | ((cs ^ (pix & 7)) & 7);
    *(bf16x8*)(&Xs[row * 17408 + pix * 256 + sw * 16]) = v;
  }
  __syncthreads();

  f32x4 acc[4][2];
#pragma unroll
  for (int i = 0; i < 4; i++)
#pragma unroll
    for (int j = 0; j < 2; j++)
      acc[i][j] = {0.f, 0.f, 0.f, 0.f};

#pragma unroll
  for (int kh = 0; kh < 3; kh++) {
#pragma unroll
    for (int kw = 0; kw < 3; kw++) {
      int shf = (kw - 1) * DIL + 2;
#pragma unroll
      for (int cs4 = 0; cs4 < 4; cs4++) {
        const unsigned short* Ap =
            Wt + ((size_t)(((kh * 3 + kw) * 4 + cs4) * 2 + wm) << 11) + lane * 8;
        bf16x8 a[4], bfr[2];
#pragma unroll
        for (int mf = 0; mf < 4; mf++)
          a[mf] = *(const bf16x8*)(Ap + (mf << 9));
#pragma unroll
        for (int nf = 0; nf < 2; nf++) {
          int px = wbase + nf * 16 + ml + shf;
          int cslot = cs4 * 4 + kg;
          int sw = (cslot & 8) | ((cslot ^ (px & 7)) & 7);
          bfr[nf] = *(const bf16x8*)(&Xs[kh * 17408 + px * 256 + sw * 16]);
        }
#pragma unroll
        for (int mf = 0; mf < 4; mf++)
#pragma unroll
          for (int nf = 0; nf < 2; nf++)
            acc[mf][nf] = __builtin_amdgcn_mfma_f32_16x16x32_bf16(
                a[mf], bfr[nf], acc[mf][nf], 0, 0, 0);
      }
    }
  }

#pragma unroll
  for (int mf = 0; mf < 4; mf++) {
    int obase = wm * 64 + mf * 16 + kg * 4;
#pragma unroll
    for (int nf = 0; nf < 2; nf++) {
      int w = wbase + nf * 16 + ml;
      float v[4];
#pragma unroll
      for (int r4 = 0; r4 < 4; r4++) {
        int o = obase + r4;
        float val = acc[mf][nf][r4] + Bi[o];
        val = val > 0.f ? val : 0.2f * val;
        size_t idx = (((size_t)bt * 128 + o) * 64 + h) * 64 + w;
        if (RES) val += Rs[idx];
        if (WF32) Yf[idx] = val;
        v[r4] = val;
      }
      if (WBF16) {
        unsigned int lo = (unsigned int)f2bf(v[0]) | ((unsigned int)f2bf(v[1]) << 16);
        unsigned int hi = (unsigned int)f2bf(v[2]) | ((unsigned int)f2bf(v[3]) << 16);
        *(uint2*)(Ybf + (((size_t)bt * 4096 + h * 64 + w) * 128 + obase)) =
            make_uint2(lo, hi);
      }
    }
  }
}

extern "C" void kernel_launch(void* const* d_in, const int* in_sizes, int n_in,
                              void* d_out, int out_size, void* d_ws, size_t ws_size,
                              hipStream_t stream) {
  (void)in_sizes; (void)n_in; (void)out_size; (void)ws_size;
  const float* x   = (const float*)d_in[0];
  const float* Wq  = (const float*)d_in[1];
  const float* bq  = (const float*)d_in[2];
  const float* Wk  = (const float*)d_in[3];
  const float* bk  = (const float*)d_in[4];
  const float* Wv  = (const float*)d_in[5];
  const float* bv  = (const float*)d_in[6];
  const float* Wo  = (const float*)d_in[7];
  const float* bo  = (const float*)d_in[8];
  const float* Wf1 = (const float*)d_in[9];
  const float* bf1 = (const float*)d_in[10];
  const float* Wf2 = (const float*)d_in[11];
  const float* bf2 = (const float*)d_in[12];
  float* out = (float*)d_out;

  // workspace layout (~91.3 MB)
  char* wsb = (char*)d_ws;
  float* xcur = (float*)(wsb);                                  // 16 MB
  float* opk  = (float*)(wsb + 16777216);                       // 16 MB
  float* S    = (float*)(wsb + 33554432);                       //  8 MB (scores / partials / flash Opart)
  unsigned short* Qp = (unsigned short*)(wsb + 41943040);       //  8 MB (g1-3)
  unsigned short* Kp = (unsigned short*)(wsb + 50331648);       //  8 MB (g1-3)
  unsigned short* Vt = (unsigned short*)(wsb + 58720256);       //  8 MB (g1-3)
  unsigned short* Qf = (unsigned short*)(wsb + 67108864);       //  2 MB (g0)
  unsigned short* Kf = (unsigned short*)(wsb + 69206016);       //  2 MB (g0)
  unsigned short* Vf = (unsigned short*)(wsb + 71303168);       //  2 MB (g0)
  unsigned short* att_hwc  = (unsigned short*)(wsb + 73400320); //  8 MB (=f1_hwc)
  unsigned short* xcur_hwc = (unsigned short*)(wsb + 81788928); //  8 MB (=Pb)
  unsigned short* Wt0 = (unsigned short*)(wsb + 90177536);
  unsigned short* Wt1 = (unsigned short*)(wsb + 90472448);
  unsigned short* Wt2 = (unsigned short*)(wsb + 90767360);
  unsigned short* Wqb = (unsigned short*)(wsb + 91062272);
  unsigned short* Wkb = (unsigned short*)(wsb + 91095040);
  unsigned short* Wvb = (unsigned short*)(wsb + 91127808);
  float* MLp = (float*)(wsb + 91160576);                        // 128 KB
  unsigned short* f1_hwc = att_hwc;
  unsigned short* Pb = xcur_hwc;

  hipMemcpyAsync(xcur, x, 16777216, hipMemcpyDeviceToDevice, stream);

  const int Ls[3] = {1024, 256, 64};
  const int Ds[3] = {512, 2048, 8192};
  dim3 blk(256);

  x2hwc<<<dim3(128, 16), blk, 0, stream>>>(x, xcur_hwc);

  for (int layer = 0; layer < 2; layer++) {
    const float* wq  = Wq  + layer * 16384;
    const float* wk  = Wk  + layer * 16384;
    const float* wv  = Wv  + layer * 16384;
    const float* bq_ = bq  + layer * 128;
    const float* bk_ = bk  + layer * 128;
    const float* bv_ = bv  + layer * 128;
    const float* wo  = Wo  + layer * 147456;
    const float* bo_ = bo  + layer * 128;
    const float* wf1 = Wf1 + layer * 147456;
    const float* bf1_ = bf1 + layer * 128;
    const float* wf2 = Wf2 + layer * 147456;
    const float* bf2_ = bf2 + layer * 128;

    wprep3<<<dim3(576, 3), blk, 0, stream>>>(wo, wf1, wf2, Wt0, Wt1, Wt2);
    wprep1<<<dim3(64, 3), blk, 0, stream>>>(wq, wk, wv, Wqb, Wkb, Wvb);

    qkv_pack<0><<<dim3(512, 2), blk, 0, stream>>>(xcur_hwc, Wqb, bq_, Qp, nullptr, Qf);
    qkv_pack<1><<<dim3(512, 2), blk, 0, stream>>>(xcur_hwc, Wkb, bk_, Kp, nullptr, Kf);
    qkv_pack<2><<<dim3(512, 2), blk, 0, stream>>>(xcur_hwc, Wvb, bv_, nullptr, Vt, Vf);

    flash_mfma<<<dim3(512, 2), blk, 0, stream>>>(Qf, Kf, Vf, S, MLp);
    flash_merge<<<dim3(1024), blk, 0, stream>>>(S, MLp, opk);

    for (int gg = 0; gg < 3; gg++) {
      int g = gg + 1;
      size_t go = (size_t)g << 20;
      int L = Ls[gg], D = Ds[gg];
      if (gg == 0) {
        gemm_tn<<<dim3(L / 64, L / 64, 2), blk, 0, stream>>>(
            Qp + go, Kp + go, S, D, D, D, L, 1LL << 19, 1LL << 19, (long long)L * L);
        softmax_bf16<<<dim3(2 * L), blk, 0, stream>>>(S, Pb, L);
      } else {
        int nsplit = D / 128;  // g2: 16, g3: 64
        gemm_tn_sk<<<dim3(L / 64, L / 64, 2 * nsplit), blk, 0, stream>>>(
            Qp + go, Kp + go, S, D, D, L, 1LL << 19, 1LL << 19);
        softmax_sum_bf16<<<dim3(2 * L), blk, 0, stream>>>(S, Pb, L, nsplit);
      }
      if (gg == 2) {
        // g3: K=64, split-K not applicable
        gemm_tn<<<dim3(D / 64, L / 64, 2), blk, 0, stream>>>(
            Pb, Vt + go, opk + go, L, L, L, D, (long long)L * L, 1LL << 19, 1LL << 19);
      } else {
        // PV split-K x2: partials into S (scores already consumed)
        gemm_tn_sk2<<<dim3(D / 64, L / 64, 4), blk, 0, stream>>>(
            Pb, Vt + go, S, L / 2, L, L, D, (long long)L * L, 1LL << 19);
        sum2<<<dim3(1024), blk, 0, stream>>>(S, opk + go, 131072, 1LL << 19);
      }
    }

    unpack_att_bf16<<<dim3(2048), blk, 0, stream>>>(opk, att_hwc);

    conv_mfma<1, true, true, true><<<dim3(512), blk, 0, stream>>>(
        att_hwc, Wt0, bo_, xcur, xcur, xcur_hwc);
    conv_mfma<2, false, true, false><<<dim3(512), blk, 0, stream>>>(
        xcur_hwc, Wt1, bf1_, nullptr, nullptr, f1_hwc);
    if (layer == 0) {
      conv_mfma<1, true, true, true><<<dim3(512), blk, 0, stream>>>(
          f1_hwc, Wt2, bf2_, xcur, xcur, xcur_hwc);
    } else {
      conv_mfma<1, true, false, true><<<dim3(512), blk, 0, stream>>>(
          f1_hwc, Wt2, bf2_, xcur, out, nullptr);
    }
  }
}

// Round 10
// 664.113 us; speedup vs baseline: 1.0019x; 1.0019x over previous
//
#include <hip/hip_runtime.h>

// ---------- bf16 helpers (manual, RNE) ----------
__device__ __forceinline__ unsigned short f2bf(float f) {
  union { float f; unsigned int i; } c; c.f = f;
  unsigned int i = c.i;
  i += 0x7fffu + ((i >> 16) & 1u);
  return (unsigned short)(i >> 16);
}

typedef __attribute__((ext_vector_type(8))) short bf16x8;
typedef __attribute__((ext_vector_type(4))) float f32x4;

// Geometry: x is (bt=8, C=128, 64, 64); bt = b*4 + t (b=2, t=4).
// Head group g (0..3): patch p = 1<<(g+1), dk = 32 channels.
// Packed token layout per group: (b, l, d); L*D = 1<<19; group base = g<<20.
// MFMA convention (verified):
//   A-frag: lane(ml=lane&15,kg=lane>>4) holds A[row=ml][c=kg*8+j]
//   B-frag: lane holds B[c=kg*8+j][col=ml]
//   C/D   : lane holds D[row=kg*4+reg][col=ml]
// g0 fragment-major layouts (contiguous 1KB per wave frag-load):
//   Qf[b][qt][cc4][lane64][8]   element (q=qt*16+ml, d=cc*32+kg*8+j)
//   Kf[b][ck64][cc4][mf4][lane64][8]  (key=ck*64+mf*16+ml, d=cc*32+kg*8+j)
//   Vf[b][ck64][nf8][part2][lane64][8] (key=ck*64+part*32+kg*8+j, d=nf*16+ml)

// ---------- x (NCHW f32) -> x_hwc (pix_g, 128) bf16 ----------
__global__ __launch_bounds__(256) void x2hwc(const float* __restrict__ X,
                                             unsigned short* __restrict__ Xh) {
  int pixg = blockIdx.x * 256 + threadIdx.x;  // 32768
  int c0 = blockIdx.y * 8;
  int bt = pixg >> 12, pix = pixg & 4095;
  const float* src = X + ((size_t)bt << 19) + (size_t)c0 * 4096 + pix;
  unsigned int pk[4];
#pragma unroll
  for (int j = 0; j < 4; j++) {
    unsigned short u0 = f2bf(src[(2 * j) * 4096]);
    unsigned short u1 = f2bf(src[(2 * j + 1) * 4096]);
    pk[j] = (unsigned int)u0 | ((unsigned int)u1 << 16);
  }
  *(uint4*)(Xh + (size_t)pixg * 128 + c0) = make_uint4(pk[0], pk[1], pk[2], pk[3]);
}

// ---------- weight prep 3x3: (o,i,3,3) f32 -> fragment-major bf16 ----------
__global__ __launch_bounds__(256) void wprep3(
    const float* __restrict__ s0, const float* __restrict__ s1,
    const float* __restrict__ s2, unsigned short* __restrict__ d0,
    unsigned short* __restrict__ d1, unsigned short* __restrict__ d2) {
  int idx = blockIdx.x * 256 + threadIdx.x;  // 147456
  const float* s = blockIdx.y == 0 ? s0 : (blockIdx.y == 1 ? s1 : s2);
  unsigned short* d = blockIdx.y == 0 ? d0 : (blockIdx.y == 1 ? d1 : d2);
  int j = idx & 7;
  int lane = (idx >> 3) & 63;
  int kg = lane >> 4, ml = lane & 15;
  int f = idx >> 9;
  int mf = f & 3, wm = (f >> 2) & 1, cs = (f >> 3) & 3, tap = f >> 5;
  int o = wm * 64 + mf * 16 + ml;
  int i = cs * 32 + kg * 8 + j;
  d[idx] = f2bf(s[(size_t)(o * 128 + i) * 9 + tap]);
}

// ---------- weight prep 1x1 ----------
__global__ __launch_bounds__(256) void wprep1(
    const float* __restrict__ s0, const float* __restrict__ s1,
    const float* __restrict__ s2, unsigned short* __restrict__ d0,
    unsigned short* __restrict__ d1, unsigned short* __restrict__ d2) {
  int idx = blockIdx.x * 256 + threadIdx.x;  // 16384
  const float* s = blockIdx.y == 0 ? s0 : (blockIdx.y == 1 ? s1 : s2);
  unsigned short* d = blockIdx.y == 0 ? d0 : (blockIdx.y == 1 ? d1 : d2);
  d[idx] = f2bf(s[idx]);
}

// ---------- QKV projection MFMA GEMM with pack epilogue ----------
template <int MODE>
__global__ __launch_bounds__(256) void qkv_pack(
    const unsigned short* __restrict__ Xh, const unsigned short* __restrict__ Wb,
    const float* __restrict__ Bi, unsigned short* __restrict__ P,
    unsigned short* __restrict__ VtP, unsigned short* __restrict__ Ff) {
  int tid = threadIdx.x, lane = tid & 63, wid = tid >> 6;
  int wm = wid & 1, wn = wid >> 1;
  int ml = lane & 15, kg = lane >> 4;
  int m_base = blockIdx.y * 64 + wm * 32;
  int n_base = blockIdx.x * 64 + wn * 32;
  f32x4 acc[2][2];
#pragma unroll
  for (int i = 0; i < 2; i++)
#pragma unroll
    for (int j = 0; j < 2; j++) acc[i][j] = {0.f, 0.f, 0.f, 0.f};
#pragma unroll
  for (int kc = 0; kc < 128; kc += 32) {
    bf16x8 af[2], bfr[2];
#pragma unroll
    for (int mf = 0; mf < 2; mf++)
      af[mf] = *(const bf16x8*)(Wb + (size_t)(m_base + mf * 16 + ml) * 128 + kc + kg * 8);
#pragma unroll
    for (int nf = 0; nf < 2; nf++)
      bfr[nf] = *(const bf16x8*)(Xh + (size_t)(n_base + nf * 16 + ml) * 128 + kc + kg * 8);
#pragma unroll
    for (int mf = 0; mf < 2; mf++)
#pragma unroll
      for (int nf = 0; nf < 2; nf++)
        acc[mf][nf] = __builtin_amdgcn_mfma_f32_16x16x32_bf16(af[mf], bfr[nf], acc[mf][nf], 0, 0, 0);
  }
#pragma unroll
  for (int mf = 0; mf < 2; mf++)
#pragma unroll
    for (int nf = 0; nf < 2; nf++)
#pragma unroll
      for (int r = 0; r < 4; r++) {
        int c = m_base + mf * 16 + kg * 4 + r;
        int pixg = n_base + nf * 16 + ml;
        float val = acc[mf][nf][r] + Bi[c];
        int bt = pixg >> 12, pix = pixg & 4095;
        int h = pix >> 6, w = pix & 63;
        int g = c >> 5, sh = g + 1, msk = (1 << sh) - 1, ohn = 64 >> sh;
        int b = bt >> 2, t_i = bt & 3;
        int l = (t_i * ohn + (h >> sh)) * ohn + (w >> sh);
        int Dg = 32 << (2 * sh);
        int d = ((c & 31) << (2 * sh)) + ((h & msk) << sh) + (w & msk);
        if (MODE == 0) val *= rsqrtf((float)Dg);
        unsigned short bv = f2bf(val);
        size_t bofs = (size_t)b << 19;
        if (g == 0) {
          if (MODE == 0) {
            int qt = l >> 4, mlq = l & 15, cc = d >> 5, kgq = (d >> 3) & 3, j = d & 7;
            Ff[bofs + ((size_t)(qt * 4 + cc) << 9) + (kgq * 16 + mlq) * 8 + j] = bv;
          } else if (MODE == 1) {
            int ck = l >> 6, mfk = (l >> 4) & 3, mlk = l & 15;
            int cc = d >> 5, kgk = (d >> 3) & 3, j = d & 7;
            Ff[bofs + ((size_t)(ck * 16 + cc * 4 + mfk) << 9) + (kgk * 16 + mlk) * 8 + j] = bv;
          } else {
            int ck = l >> 6, part = (l >> 5) & 1, kgv = (l >> 3) & 3, j = l & 7;
            int nf = d >> 4, mlv = d & 15;
            Ff[bofs + ((size_t)(ck * 16 + nf * 2 + part) << 9) + (kgv * 16 + mlv) * 8 + j] = bv;
          }
        } else {
          size_t base = ((size_t)g << 20) + bofs;
          if (MODE != 2) {
            P[base + (size_t)l * Dg + d] = bv;
          } else {
            int Lg = 16384 >> (2 * sh);
            VtP[base + (size_t)d * Lg + l] = bv;
          }
        }
      }
}

// ---------- generic MFMA GEMM: C(MxN) f32 = A(MxK) * B(NxK)^T, bf16 ----------
__global__ __launch_bounds__(256) void gemm_tn(
    const unsigned short* __restrict__ A, const unsigned short* __restrict__ B,
    float* __restrict__ C, int K, int lda, int ldb, int ldc,
    long long sA, long long sB, long long sC) {
  int tid = threadIdx.x, lane = tid & 63, wid = tid >> 6;
  int wm = wid & 1, wn = wid >> 1;
  int ml = lane & 15, kg = lane >> 4;
  A += (size_t)blockIdx.z * sA;
  B += (size_t)blockIdx.z * sB;
  C += (size_t)blockIdx.z * sC;
  int m_base = blockIdx.y * 64 + wm * 32;
  int n_base = blockIdx.x * 64 + wn * 32;
  f32x4 acc[2][2];
#pragma unroll
  for (int i = 0; i < 2; i++)
#pragma unroll
    for (int j = 0; j < 2; j++) acc[i][j] = {0.f, 0.f, 0.f, 0.f};
  for (int kc = 0; kc < K; kc += 32) {
    bf16x8 af[2], bfr[2];
#pragma unroll
    for (int mf = 0; mf < 2; mf++)
      af[mf] = *(const bf16x8*)(A + (size_t)(m_base + mf * 16 + ml) * lda + kc + kg * 8);
#pragma unroll
    for (int nf = 0; nf < 2; nf++)
      bfr[nf] = *(const bf16x8*)(B + (size_t)(n_base + nf * 16 + ml) * ldb + kc + kg * 8);
#pragma unroll
    for (int mf = 0; mf < 2; mf++)
#pragma unroll
      for (int nf = 0; nf < 2; nf++)
        acc[mf][nf] = __builtin_amdgcn_mfma_f32_16x16x32_bf16(af[mf], bfr[nf], acc[mf][nf], 0, 0, 0);
  }
#pragma unroll
  for (int mf = 0; mf < 2; mf++)
#pragma unroll
    for (int nf = 0; nf < 2; nf++)
#pragma unroll
      for (int r = 0; r < 4; r++) {
        int m = m_base + mf * 16 + kg * 4 + r;
        int n = n_base + nf * 16 + ml;
        C[(size_t)m * ldc + n] = acc[mf][nf][r];
      }
}

// ---------- split-K MFMA GEMM (square, KC=128): partial tiles ----------
__global__ __launch_bounds__(256) void gemm_tn_sk(
    const unsigned short* __restrict__ A, const unsigned short* __restrict__ B,
    float* __restrict__ Cp, int lda, int ldb, int L,
    long long sA, long long sB) {
  constexpr int KC = 128;
  int tid = threadIdx.x, lane = tid & 63, wid = tid >> 6;
  int wm = wid & 1, wn = wid >> 1;
  int ml = lane & 15, kg = lane >> 4;
  int bz = blockIdx.z, b = bz & 1, split = bz >> 1;
  A += (size_t)b * sA + split * KC;
  B += (size_t)b * sB + split * KC;
  float* Ct = Cp + (size_t)bz * L * L;
  int m_base = blockIdx.y * 64 + wm * 32;
  int n_base = blockIdx.x * 64 + wn * 32;
  f32x4 acc[2][2];
#pragma unroll
  for (int i = 0; i < 2; i++)
#pragma unroll
    for (int j = 0; j < 2; j++) acc[i][j] = {0.f, 0.f, 0.f, 0.f};
#pragma unroll
  for (int kc = 0; kc < KC; kc += 32) {
    bf16x8 af[2], bfr[2];
#pragma unroll
    for (int mf = 0; mf < 2; mf++)
      af[mf] = *(const bf16x8*)(A + (size_t)(m_base + mf * 16 + ml) * lda + kc + kg * 8);
#pragma unroll
    for (int nf = 0; nf < 2; nf++)
      bfr[nf] = *(const bf16x8*)(B + (size_t)(n_base + nf * 16 + ml) * ldb + kc + kg * 8);
#pragma unroll
    for (int mf = 0; mf < 2; mf++)
#pragma unroll
      for (int nf = 0; nf < 2; nf++)
        acc[mf][nf] = __builtin_amdgcn_mfma_f32_16x16x32_bf16(af[mf], bfr[nf], acc[mf][nf], 0, 0, 0);
  }
#pragma unroll
  for (int mf = 0; mf < 2; mf++)
#pragma unroll
    for (int nf = 0; nf < 2; nf++)
#pragma unroll
      for (int r = 0; r < 4; r++) {
        int m = m_base + mf * 16 + kg * 4 + r;
        int n = n_base + nf * 16 + ml;
        Ct[(size_t)m * L + n] = acc[mf][nf][r];
      }
}

// ---------- split-K MFMA GEMM, 2 splits, general ldc (for PV) ----------
__global__ __launch_bounds__(256) void gemm_tn_sk2(
    const unsigned short* __restrict__ A, const unsigned short* __restrict__ B,
    float* __restrict__ Cp, int KC, int lda, int ldb, int ldc,
    long long sA, long long sB) {
  int tid = threadIdx.x, lane = tid & 63, wid = tid >> 6;
  int wm = wid & 1, wn = wid >> 1;
  int ml = lane & 15, kg = lane >> 4;
  int bz = blockIdx.z, b = bz & 1, split = bz >> 1;
  A += (size_t)b * sA + (size_t)split * KC;
  B += (size_t)b * sB + (size_t)split * KC;
  size_t MN = (size_t)gridDim.y * 64 * ldc;
  float* Ct = Cp + (size_t)bz * MN;
  int m_base = blockIdx.y * 64 + wm * 32;
  int n_base = blockIdx.x * 64 + wn * 32;
  f32x4 acc[2][2];
#pragma unroll
  for (int i = 0; i < 2; i++)
#pragma unroll
    for (int j = 0; j < 2; j++) acc[i][j] = {0.f, 0.f, 0.f, 0.f};
  for (int kc = 0; kc < KC; kc += 32) {
    bf16x8 af[2], bfr[2];
#pragma unroll
    for (int mf = 0; mf < 2; mf++)
      af[mf] = *(const bf16x8*)(A + (size_t)(m_base + mf * 16 + ml) * lda + kc + kg * 8);
#pragma unroll
    for (int nf = 0; nf < 2; nf++)
      bfr[nf] = *(const bf16x8*)(B + (size_t)(n_base + nf * 16 + ml) * ldb + kc + kg * 8);
#pragma unroll
    for (int mf = 0; mf < 2; mf++)
#pragma unroll
      for (int nf = 0; nf < 2; nf++)
        acc[mf][nf] = __builtin_amdgcn_mfma_f32_16x16x32_bf16(af[mf], bfr[nf], acc[mf][nf], 0, 0, 0);
  }
#pragma unroll
  for (int mf = 0; mf < 2; mf++)
#pragma unroll
    for (int nf = 0; nf < 2; nf++)
#pragma unroll
      for (int r = 0; r < 4; r++) {
        int m = m_base + mf * 16 + kg * 4 + r;
        int n = n_base + nf * 16 + ml;
        Ct[(size_t)m * ldc + n] = acc[mf][nf][r];
      }
}

// ---------- sum 2 split-K partials -> Out (f32, batch stride sOut) ----------
__global__ __launch_bounds__(256) void sum2(const float* __restrict__ Cp,
                                            float* __restrict__ Out,
                                            int MNq, long long sOut) {
  int idx = blockIdx.x * 256 + threadIdx.x;  // 2*MNq
  int b = idx / MNq, r = idx - b * MNq;
  const float4* c4 = (const float4*)Cp;
  float4 v0 = c4[(size_t)b * MNq + r];
  float4 v1 = c4[(size_t)(2 + b) * MNq + r];
  float4 o = make_float4(v0.x + v1.x, v0.y + v1.y, v0.z + v1.z, v0.w + v1.w);
  ((float4*)(Out + (size_t)b * sOut))[r] = o;
}

// ---------- sum partials + row softmax -> bf16 (L <= 256) ----------
__global__ __launch_bounds__(256) void softmax_sum_bf16(
    const float* __restrict__ Sp, unsigned short* __restrict__ P, int L, int nsplit) {
  __shared__ float red[256];
  int tid = threadIdx.x;
  int b = blockIdx.x / L, m = blockIdx.x - b * L;
  const float* row = Sp + ((size_t)b * L + m) * L;
  long long pstride = 2LL * L * L;
  float val = 0.f;
  if (tid < L) {
    for (int s = 0; s < nsplit; s++) val += row[(size_t)s * pstride + tid];
  }
  red[tid] = (tid < L) ? val : -1e30f;
  __syncthreads();
  for (int s = 128; s > 0; s >>= 1) {
    if (tid < s) red[tid] = fmaxf(red[tid], red[tid + s]);
    __syncthreads();
  }
  float mx = red[0]; __syncthreads();
  float e = (tid < L) ? __expf(val - mx) : 0.f;
  red[tid] = e; __syncthreads();
  for (int s = 128; s > 0; s >>= 1) {
    if (tid < s) red[tid] += red[tid + s];
    __syncthreads();
  }
  float inv = 1.f / red[0];
  if (tid < L) P[((size_t)b * L + m) * L + tid] = f2bf(e * inv);
}

// ---------- row softmax f32 -> bf16 (large L) ----------
__global__ __launch_bounds__(256) void softmax_bf16(float* __restrict__ S,
                                                    unsigned short* __restrict__ P, int L) {
  __shared__ float red[256];
  int tid = threadIdx.x;
  float* p = S + (size_t)blockIdx.x * L;
  unsigned short* o = P + (size_t)blockIdx.x * L;
  float mx = -1e30f;
  for (int e = tid; e < L; e += 256) mx = fmaxf(mx, p[e]);
  red[tid] = mx; __syncthreads();
  for (int s = 128; s > 0; s >>= 1) {
    if (tid < s) red[tid] = fmaxf(red[tid], red[tid + s]);
    __syncthreads();
  }
  mx = red[0]; __syncthreads();
  float sm = 0.f;
  for (int e = tid; e < L; e += 256) {
    float v = __expf(p[e] - mx);
    p[e] = v; sm += v;
  }
  red[tid] = sm; __syncthreads();
  for (int s = 128; s > 0; s >>= 1) {
    if (tid < s) red[tid] += red[tid + s];
    __syncthreads();
  }
  float inv = 1.f / red[0];
  for (int e = tid; e < L; e += 256) o[e] = f2bf(p[e] * inv);
}

// ---------- MFMA flash attention group 0, v3: 64-q blocks, wave-private q-tiles ----------
// grid (128, 4): bx -> (b, qt4); each wave owns q-tile qt4*4+wv (16 q).
// by = K-quarter (1024 keys = 16 chunks). All 4 waves walk the SAME chunks in
// lockstep (__syncthreads per chunk) -> identical K/V frag addresses -> L1 reuse;
// L2 traffic drops 4x vs per-block-private key ranges.
// Outputs UNNORMALIZED O~ per quarter + (M,L); flash_merge4 combines.
__global__ __launch_bounds__(256, 2) void flash_mfma(
    const unsigned short* __restrict__ Qf, const unsigned short* __restrict__ Kf,
    const unsigned short* __restrict__ Vf, float* __restrict__ O01,
    float* __restrict__ O23, float* __restrict__ MLp) {
  __shared__ unsigned short Pl[4][16][72];
  int tid = threadIdx.x, lane = tid & 63, wv = tid >> 6;
  int ml = lane & 15, kg = lane >> 4;
  int b = blockIdx.x >> 6, qt4 = blockIdx.x & 63;
  int qt = qt4 * 4 + wv;
  int quarter = blockIdx.y;
  size_t bofs = (size_t)b << 19;
  int q0 = qt * 16;

  bf16x8 qf[4];
#pragma unroll
  for (int cc = 0; cc < 4; cc++)
    qf[cc] = *(const bf16x8*)(Qf + bofs + ((size_t)(qt * 4 + cc) << 9) + lane * 8);

  float m_i = -1e30f, l_i = 0.f;
  f32x4 of[8];
#pragma unroll
  for (int nf = 0; nf < 8; nf++) of[nf] = {0.f, 0.f, 0.f, 0.f};

  for (int ck = quarter * 16; ck < quarter * 16 + 16; ck++) {
    __syncthreads();  // keep waves in lockstep so identical K/V loads hit L1
    const unsigned short* Kc = Kf + bofs + ((size_t)ck << 13);
    const unsigned short* Vc = Vf + bofs + ((size_t)ck << 13);
    // S^T = K x Q
    f32x4 st[4];
#pragma unroll
    for (int mf = 0; mf < 4; mf++) st[mf] = {0.f, 0.f, 0.f, 0.f};
    __builtin_amdgcn_s_setprio(1);
#pragma unroll
    for (int cc = 0; cc < 4; cc++)
#pragma unroll
      for (int mf = 0; mf < 4; mf++) {
        bf16x8 kf = *(const bf16x8*)(Kc + ((cc * 4 + mf) << 9) + lane * 8);
        st[mf] = __builtin_amdgcn_mfma_f32_16x16x32_bf16(kf, qf[cc], st[mf], 0, 0, 0);
      }
    __builtin_amdgcn_s_setprio(0);
    // hoist V loads: latency hides under the softmax chain
    bf16x8 vf[16];
#pragma unroll
    for (int nv = 0; nv < 16; nv++)
      vf[nv] = *(const bf16x8*)(Vc + (nv << 9) + lane * 8);
    // online softmax for q = ml
    float cmax = -1e30f;
#pragma unroll
    for (int mf = 0; mf < 4; mf++)
#pragma unroll
      for (int r = 0; r < 4; r++) cmax = fmaxf(cmax, st[mf][r]);
    cmax = fmaxf(cmax, __shfl_xor(cmax, 16));
    cmax = fmaxf(cmax, __shfl_xor(cmax, 32));
    int skip = __all(cmax <= m_i);  // wave-uniform; alpha==1 path is exact
    float mnew = skip ? m_i : fmaxf(m_i, cmax);
    float p[4][4];
    float psum = 0.f;
#pragma unroll
    for (int mf = 0; mf < 4; mf++)
#pragma unroll
      for (int r = 0; r < 4; r++) {
        float pv = __expf(st[mf][r] - mnew);
        p[mf][r] = pv; psum += pv;
      }
    psum += __shfl_xor(psum, 16);
    psum += __shfl_xor(psum, 32);
    if (skip) {
      l_i += psum;
    } else {
      float alpha = __expf(m_i - mnew);
      l_i = l_i * alpha + psum;
      m_i = mnew;
      float a0 = __shfl(alpha, kg * 4 + 0), a1 = __shfl(alpha, kg * 4 + 1);
      float a2 = __shfl(alpha, kg * 4 + 2), a3 = __shfl(alpha, kg * 4 + 3);
#pragma unroll
      for (int nf = 0; nf < 8; nf++) {
        of[nf][0] *= a0; of[nf][1] *= a1; of[nf][2] *= a2; of[nf][3] *= a3;
      }
    }
#pragma unroll
    for (int mf = 0; mf < 4; mf++) {
      unsigned int lo = (unsigned int)f2bf(p[mf][0]) | ((unsigned int)f2bf(p[mf][1]) << 16);
      unsigned int hi = (unsigned int)f2bf(p[mf][2]) | ((unsigned int)f2bf(p[mf][3]) << 16);
      *(uint2*)&Pl[wv][ml][mf * 16 + kg * 4] = make_uint2(lo, hi);
    }
    bf16x8 pa0 = *(const bf16x8*)&Pl[wv][ml][kg * 8];
    bf16x8 pa1 = *(const bf16x8*)&Pl[wv][ml][32 + kg * 8];
    __builtin_amdgcn_s_setprio(1);
#pragma unroll
    for (int nf = 0; nf < 8; nf++) {
      of[nf] = __builtin_amdgcn_mfma_f32_16x16x32_bf16(pa0, vf[nf * 2 + 0], of[nf], 0, 0, 0);
      of[nf] = __builtin_amdgcn_mfma_f32_16x16x32_bf16(pa1, vf[nf * 2 + 1], of[nf], 0, 0, 0);
    }
    __builtin_amdgcn_s_setprio(0);
  }

  // per-wave epilogue: unnormalized O~ + (m, l); no cross-wave merge needed
  float* Op = (quarter < 2) ? (O01 + ((size_t)quarter << 20))
                            : (O23 + ((size_t)(quarter - 2) << 20));
  if (kg == 0) {
    MLp[quarter * 16384 + b * 8192 + q0 + ml] = m_i;
    MLp[quarter * 16384 + b * 8192 + 4096 + q0 + ml] = l_i;
  }
#pragma unroll
  for (int nf = 0; nf < 8; nf++)
#pragma unroll
    for (int r = 0; r < 4; r++)
      Op[bofs + (size_t)(q0 + kg * 4 + r) * 128 + nf * 16 + ml] = of[nf][r];
}

// ---------- merge the four flash K-quarters ----------
__global__ __launch_bounds__(256) void flash_merge4(
    const float* __restrict__ O01, const float* __restrict__ O23,
    const float* __restrict__ MLp, float* __restrict__ O) {
  int idx = blockIdx.x * 256 + threadIdx.x;  // 262144: (b, q, d4)
  int b = idx >> 17, rem = idx & 131071;
  int q = rem >> 5, d4 = (rem & 31) << 2;
  float Ms[4], Ls[4];
  float M = -1e30f;
#pragma unroll
  for (int s = 0; s < 4; s++) {
    Ms[s] = MLp[s * 16384 + b * 8192 + q];
    Ls[s] = MLp[s * 16384 + b * 8192 + 4096 + q];
    M = fmaxf(M, Ms[s]);
  }
  float es[4];
  float den = 0.f;
#pragma unroll
  for (int s = 0; s < 4; s++) {
    es[s] = __expf(Ms[s] - M);
    den += es[s] * Ls[s];
  }
  float inv = 1.f / den;
  size_t o0 = ((size_t)b << 19) + (size_t)q * 128 + d4;
  float4 a0 = *(const float4*)(O01 + o0);
  float4 a1 = *(const float4*)(O01 + (1 << 20) + o0);
  float4 a2 = *(const float4*)(O23 + o0);
  float4 a3 = *(const float4*)(O23 + (1 << 20) + o0);
  float4 r;
  r.x = (es[0] * a0.x + es[1] * a1.x + es[2] * a2.x + es[3] * a3.x) * inv;
  r.y = (es[0] * a0.y + es[1] * a1.y + es[2] * a2.y + es[3] * a3.y) * inv;
  r.z = (es[0] * a0.z + es[1] * a1.z + es[2] * a2.z + es[3] * a3.z) * inv;
  r.w = (es[0] * a0.w + es[1] * a1.w + es[2] * a2.w + es[3] * a3.w) * inv;
  *(float4*)(O + o0) = r;
}

// ---------- unpack packed attention output to bf16 (bt,h,w,C) ----------
__global__ __launch_bounds__(256) void unpack_att_bf16(
    const float* __restrict__ opk, unsigned short* __restrict__ att) {
  int idx = blockIdx.x * 256 + threadIdx.x;
  int oct = idx & 15, pix = idx >> 4;
  int w = pix & 63, h = (pix >> 6) & 63, bt = pix >> 12;
  int c0 = oct * 8;
  int g = c0 >> 5;
  int sh = g + 1, msk = (1 << sh) - 1;
  int ohn = 64 >> sh;
  int b = bt >> 2, t_i = bt & 3;
  int l = (t_i * ohn + (h >> sh)) * ohn + (w >> sh);
  int Dg = 32 << (2 * sh);
  int dbase = ((c0 & 31) << (2 * sh)) + ((h & msk) << sh) + (w & msk);
  const float* src = opk + ((size_t)g << 20) + ((size_t)b << 19) + (size_t)l * Dg;
  int dstep = 1 << (2 * sh);
  unsigned int pk[4];
#pragma unroll
  for (int j = 0; j < 4; j++) {
    unsigned short u0 = f2bf(src[dbase + (2 * j) * dstep]);
    unsigned short u1 = f2bf(src[dbase + (2 * j + 1) * dstep]);
    pk[j] = (unsigned int)u0 | ((unsigned int)u1 << 16);
  }
  *(uint4*)(att + ((size_t)pix * 128 + c0)) = make_uint4(pk[0], pk[1], pk[2], pk[3]);
}

// ---------- MFMA implicit-GEMM 3x3 conv: LDS row-staged, frag-major weights ----------
template <int DIL, bool WF32, bool WBF16, bool RES>
__global__ __launch_bounds__(256) void conv_mfma(
    const unsigned short* __restrict__ Xb,
    const unsigned short* __restrict__ Wt,
    const float* __restrict__ Bi,
    const float* __restrict__ Rs,
    float* __restrict__ Yf,
    unsigned short* __restrict__ Ybf) {
  __shared__ __align__(16) char Xs[3 * 17408];
  int tid = threadIdx.x;
  int lane = tid & 63, wid = tid >> 6;
  int wm = wid & 1, wn = wid >> 1;
  int ml = lane & 15, kg = lane >> 4;
  int bt = blockIdx.x >> 6, h = blockIdx.x & 63;
  const int wbase = wn * 32;

  for (int idx = tid; idx < 3264; idx += 256) {
    int row = idx / 1088, rem = idx - row * 1088;
    int pix = rem >> 4, cs = rem & 15;
    int r = h + (row - 1) * DIL;
    int w = pix - 2;
    bf16x8 v = {0, 0, 0, 0, 0, 0, 0, 0};
    if ((unsigned)r < 64u && (unsigned)w < 64u)
      v = *(const bf16x8*)(Xb + (((size_t)(bt * 64 + r) * 64 + w) << 7) + cs * 8);
    int sw = (cs & 8) | ((cs ^ (pix & 7)) & 7);
    *(bf16x8*)(&Xs[row * 17408 + pix * 256 + sw * 16]) = v;
  }
  __syncthreads();

  f32x4 acc[4][2];
#pragma unroll
  for (int i = 0; i < 4; i++)
#pragma unroll
    for (int j = 0; j < 2; j++)
      acc[i][j] = {0.f, 0.f, 0.f, 0.f};

#pragma unroll
  for (int kh = 0; kh < 3; kh++) {
#pragma unroll
    for (int kw = 0; kw < 3; kw++) {
      int shf = (kw - 1) * DIL + 2;
#pragma unroll
      for (int cs4 = 0; cs4 < 4; cs4++) {
        const unsigned short* Ap =
            Wt + ((size_t)(((kh * 3 + kw) * 4 + cs4) * 2 + wm) << 11) + lane * 8;
        bf16x8 a[4], bfr[2];
#pragma unroll
        for (int mf = 0; mf < 4; mf++)
          a[mf] = *(const bf16x8*)(Ap + (mf << 9));
#pragma unroll
        for (int nf = 0; nf < 2; nf++) {
          int px = wbase + nf * 16 + ml + shf;
          int cslot = cs4 * 4 + kg;
          int sw = (cslot & 8) | ((cslot ^ (px & 7)) & 7);
          bfr[nf] = *(const bf16x8*)(&Xs[kh * 17408 + px * 256 + sw * 16]);
        }
#pragma unroll
        for (int mf = 0; mf < 4; mf++)
#pragma unroll
          for (int nf = 0; nf < 2; nf++)
            acc[mf][nf] = __builtin_amdgcn_mfma_f32_16x16x32_bf16(
                a[mf], bfr[nf], acc[mf][nf], 0, 0, 0);
      }
    }
  }

#pragma unroll
  for (int mf = 0; mf < 4; mf++) {
    int obase = wm * 64 + mf * 16 + kg * 4;
#pragma unroll
    for (int nf = 0; nf < 2; nf++) {
      int w = wbase + nf * 16 + ml;
      float v[4];
#pragma unroll
      for (int r4 = 0; r4 < 4; r4++) {
        int o = obase + r4;
        float val = acc[mf][nf][r4] + Bi[o];
        val = val > 0.f ? val : 0.2f * val;
        size_t idx = (((size_t)bt * 128 + o) * 64 + h) * 64 + w;
        if (RES) val += Rs[idx];
        if (WF32) Yf[idx] = val;
        v[r4] = val;
      }
      if (WBF16) {
        unsigned int lo = (unsigned int)f2bf(v[0]) | ((unsigned int)f2bf(v[1]) << 16);
        unsigned int hi = (unsigned int)f2bf(v[2]) | ((unsigned int)f2bf(v[3]) << 16);
        *(uint2*)(Ybf + (((size_t)bt * 4096 + h * 64 + w) * 128 + obase)) =
            make_uint2(lo, hi);
      }
    }
  }
}

extern "C" void kernel_launch(void* const* d_in, const int* in_sizes, int n_in,
                              void* d_out, int out_size, void* d_ws, size_t ws_size,
                              hipStream_t stream) {
  (void)in_sizes; (void)n_in; (void)out_size; (void)ws_size;
  const float* x   = (const float*)d_in[0];
  const float* Wq  = (const float*)d_in[1];
  const float* bq  = (const float*)d_in[2];
  const float* Wk  = (const float*)d_in[3];
  const float* bk  = (const float*)d_in[4];
  const float* Wv  = (const float*)d_in[5];
  const float* bv  = (const float*)d_in[6];
  const float* Wo  = (const float*)d_in[7];
  const float* bo  = (const float*)d_in[8];
  const float* Wf1 = (const float*)d_in[9];
  const float* bf1 = (const float*)d_in[10];
  const float* Wf2 = (const float*)d_in[11];
  const float* bf2 = (const float*)d_in[12];
  float* out = (float*)d_out;

  // workspace layout (~91.5 MB)
  char* wsb = (char*)d_ws;
  float* xcur = (float*)(wsb);                                  // 16 MB
  float* opk  = (float*)(wsb + 16777216);                       // 16 MB
  float* S    = (float*)(wsb + 33554432);                       //  8 MB (scores / partials / flash Opart q0-1)
  unsigned short* Qp = (unsigned short*)(wsb + 41943040);       //  8 MB (g1-3)
  unsigned short* Kp = (unsigned short*)(wsb + 50331648);       //  8 MB (g1-3)
  unsigned short* Vt = (unsigned short*)(wsb + 58720256);       //  8 MB (g1-3)
  unsigned short* Qf = (unsigned short*)(wsb + 67108864);       //  2 MB (g0)
  unsigned short* Kf = (unsigned short*)(wsb + 69206016);       //  2 MB (g0)
  unsigned short* Vf = (unsigned short*)(wsb + 71303168);       //  2 MB (g0)
  unsigned short* att_hwc  = (unsigned short*)(wsb + 73400320); //  8 MB (=f1_hwc; flash Opart q2-3 during attn)
  unsigned short* xcur_hwc = (unsigned short*)(wsb + 81788928); //  8 MB (=Pb)
  unsigned short* Wt0 = (unsigned short*)(wsb + 90177536);
  unsigned short* Wt1 = (unsigned short*)(wsb + 90472448);
  unsigned short* Wt2 = (unsigned short*)(wsb + 90767360);
  unsigned short* Wqb = (unsigned short*)(wsb + 91062272);
  unsigned short* Wkb = (unsigned short*)(wsb + 91095040);
  unsigned short* Wvb = (unsigned short*)(wsb + 91127808);
  float* MLp = (float*)(wsb + 91160576);                        // 256 KB
  unsigned short* f1_hwc = att_hwc;
  unsigned short* Pb = xcur_hwc;
  float* Opart23 = (float*)att_hwc;  // free during attention phase

  hipMemcpyAsync(xcur, x, 16777216, hipMemcpyDeviceToDevice, stream);

  const int Ls[3] = {1024, 256, 64};
  const int Ds[3] = {512, 2048, 8192};
  dim3 blk(256);

  x2hwc<<<dim3(128, 16), blk, 0, stream>>>(x, xcur_hwc);

  for (int layer = 0; layer < 2; layer++) {
    const float* wq  = Wq  + layer * 16384;
    const float* wk  = Wk  + layer * 16384;
    const float* wv  = Wv  + layer * 16384;
    const float* bq_ = bq  + layer * 128;
    const float* bk_ = bk  + layer * 128;
    const float* bv_ = bv  + layer * 128;
    const float* wo  = Wo  + layer * 147456;
    const float* bo_ = bo  + layer * 128;
    const float* wf1 = Wf1 + layer * 147456;
    const float* bf1_ = bf1 + layer * 128;
    const float* wf2 = Wf2 + layer * 147456;
    const float* bf2_ = bf2 + layer * 128;

    wprep3<<<dim3(576, 3), blk, 0, stream>>>(wo, wf1, wf2, Wt0, Wt1, Wt2);
    wprep1<<<dim3(64, 3), blk, 0, stream>>>(wq, wk, wv, Wqb, Wkb, Wvb);

    qkv_pack<0><<<dim3(512, 2), blk, 0, stream>>>(xcur_hwc, Wqb, bq_, Qp, nullptr, Qf);
    qkv_pack<1><<<dim3(512, 2), blk, 0, stream>>>(xcur_hwc, Wkb, bk_, Kp, nullptr, Kf);
    qkv_pack<2><<<dim3(512, 2), blk, 0, stream>>>(xcur_hwc, Wvb, bv_, nullptr, Vt, Vf);

    flash_mfma<<<dim3(128, 4), blk, 0, stream>>>(Qf, Kf, Vf, S, Opart23, MLp);
    flash_merge4<<<dim3(1024), blk, 0, stream>>>(S, Opart23, MLp, opk);

    for (int gg = 0; gg < 3; gg++) {
      int g = gg + 1;
      size_t go = (size_t)g << 20;
      int L = Ls[gg], D = Ds[gg];
      if (gg == 0) {
        gemm_tn<<<dim3(L / 64, L / 64, 2), blk, 0, stream>>>(
            Qp + go, Kp + go, S, D, D, D, L, 1LL << 19, 1LL << 19, (long long)L * L);
        softmax_bf16<<<dim3(2 * L), blk, 0, stream>>>(S, Pb, L);
      } else {
        int nsplit = D / 128;  // g2: 16, g3: 64
        gemm_tn_sk<<<dim3(L / 64, L / 64, 2 * nsplit), blk, 0, stream>>>(
            Qp + go, Kp + go, S, D, D, L, 1LL << 19, 1LL << 19);
        softmax_sum_bf16<<<dim3(2 * L), blk, 0, stream>>>(S, Pb, L, nsplit);
      }
      if (gg == 2) {
        gemm_tn<<<dim3(D / 64, L / 64, 2), blk, 0, stream>>>(
            Pb, Vt + go, opk + go, L, L, L, D, (long long)L * L, 1LL << 19, 1LL << 19);
      } else {
        gemm_tn_sk2<<<dim3(D / 64, L / 64, 4), blk, 0, stream>>>(
            Pb, Vt + go, S, L / 2, L, L, D, (long long)L * L, 1LL << 19);
        sum2<<<dim3(1024), blk, 0, stream>>>(S, opk + go, 131072, 1LL << 19);
      }
    }

    unpack_att_bf16<<<dim3(2048), blk, 0, stream>>>(opk, att_hwc);

    conv_mfma<1, true, true, true><<<dim3(512), blk, 0, stream>>>(
        att_hwc, Wt0, bo_, xcur, xcur, xcur_hwc);
    conv_mfma<2, false, true, false><<<dim3(512), blk, 0, stream>>>(
        xcur_hwc, Wt1, bf1_, nullptr, nullptr, f1_hwc);
    if (layer == 0) {
      conv_mfma<1, true, true, true><<<dim3(512), blk, 0, stream>>>(
          f1_hwc, Wt2, bf2_, xcur, xcur, xcur_hwc);
    } else {
      conv_mfma<1, true, false, true><<<dim3(512), blk, 0, stream>>>(
          f1_hwc, Wt2, bf2_, xcur, out, nullptr);
    }
  }
}